// Round 1
// baseline (29.952 us; speedup 1.0000x reference)
//
#include <hip/hip_runtime.h>
#include <math.h>

// ---- Tsit5 coefficients (double) ----
#define DH   0.01
#define CA21 0.161
#define CA31 (-0.008480655492356989)
#define CA32 0.335480655492357
#define CA41 2.8971530571054935
#define CA42 (-6.359448489975075)
#define CA43 4.3622954328695815
#define CA51 5.325864828439257
#define CA52 (-11.748883564062828)
#define CA53 7.4955393428898365
#define CA54 (-0.09249506636175525)
#define CA61 5.86145544294642
#define CA62 (-12.92096931784711)
#define CA63 8.159367898576159
#define CA64 (-0.071584973281401)
#define CA65 (-0.028269050394068383)
#define CB1  0.09646076681806523
#define CB2  0.01
#define CB3  0.4798896504144996
#define CB4  1.379008574103742
#define CB5  (-3.290069515436081)
#define CB6  2.324710524099774

// Linear part: f(u,d) = (d, -25u - 10d + F_stage)
__device__ __forceinline__ void rk_probe(double yu, double yd, const double F[6],
                                         double& ou, double& od) {
    const double h = DH;
    double k1u = yd;
    double k1d = -25.0*yu - 10.0*yd + F[0];
    double tu, td;
    tu = yu + h*(CA21*k1u); td = yd + h*(CA21*k1d);
    double k2u = td, k2d = -25.0*tu - 10.0*td + F[1];
    tu = yu + h*(CA31*k1u + CA32*k2u); td = yd + h*(CA31*k1d + CA32*k2d);
    double k3u = td, k3d = -25.0*tu - 10.0*td + F[2];
    tu = yu + h*(CA41*k1u + CA42*k2u + CA43*k3u);
    td = yd + h*(CA41*k1d + CA42*k2d + CA43*k3d);
    double k4u = td, k4d = -25.0*tu - 10.0*td + F[3];
    tu = yu + h*(CA51*k1u + CA52*k2u + CA53*k3u + CA54*k4u);
    td = yd + h*(CA51*k1d + CA52*k2d + CA53*k3d + CA54*k4d);
    double k5u = td, k5d = -25.0*tu - 10.0*td + F[4];
    tu = yu + h*(CA61*k1u + CA62*k2u + CA63*k3u + CA64*k4u + CA65*k5u);
    td = yd + h*(CA61*k1d + CA62*k2d + CA63*k3d + CA64*k4d + CA65*k5d);
    double k6u = td, k6d = -25.0*tu - 10.0*td + F[5];
    ou = yu + h*(CB1*k1u + CB2*k2u + CB3*k3u + CB4*k4u + CB5*k5u + CB6*k6u);
    od = yd + h*(CB1*k1d + CB2*k2d + CB3*k3d + CB4*k4d + CB5*k5d + CB6*k6d);
}

// ws layout (floats): [0..3]=M2 row-major, [4..5]=gvec2, [6..7]=pad,
// [8 + m*8 + k]      = Q_k^u(m)   k=0..3
// [8 + m*8 + 4 + k]  = Q_k^d(m)   m=0..48
__global__ void ndp_setup(float* __restrict__ ws) {
    int t = threadIdx.x;

    // v_i: stage-forcing response vectors; M: homogeneous propagator
    double vu[6], vd[6];
    {
        double F[6];
        #pragma unroll
        for (int i = 0; i < 6; ++i) {
            #pragma unroll
            for (int j = 0; j < 6; ++j) F[j] = 0.0;
            F[i] = 1.0;
            rk_probe(0.0, 0.0, F, vu[i], vd[i]);
        }
    }
    double Fz[6] = {0,0,0,0,0,0};
    double m00, m10, m01, m11;
    rk_probe(1.0, 0.0, Fz, m00, m10);
    rk_probe(0.0, 1.0, Fz, m01, m11);

    // scalar p dynamics: stage multipliers gam[i], per-step ratio r
    const double h = DH;
    double gam[6];
    double k1 = -1.0; gam[0] = 1.0;
    gam[1] = 1.0 + h*CA21*k1;                          double k2 = -gam[1];
    gam[2] = 1.0 + h*(CA31*k1 + CA32*k2);              double k3 = -gam[2];
    gam[3] = 1.0 + h*(CA41*k1 + CA42*k2 + CA43*k3);    double k4 = -gam[3];
    gam[4] = 1.0 + h*(CA51*k1 + CA52*k2 + CA53*k3 + CA54*k4);          double k5 = -gam[4];
    gam[5] = 1.0 + h*(CA61*k1 + CA62*k2 + CA63*k3 + CA64*k4 + CA65*k5); double k6 = -gam[5];
    double r = 1.0 + h*(CB1*k1 + CB2*k2 + CB3*k3 + CB4*k4 + CB5*k5 + CB6*k6);

    // RBF constants: C_k = exp(-k/3), H_k = 4/C_k
    double C[4], H[4];
    #pragma unroll
    for (int k = 0; k < 4; ++k) { C[k] = exp(-(double)k / 3.0); H[k] = 4.0 / C[k]; }

    if (t < 49) {
        double qu[2][4], qd[2][4];
        #pragma unroll
        for (int s = 0; s < 2; ++s)
            #pragma unroll
            for (int k = 0; k < 4; ++k) { qu[s][k] = 0.0; qd[s][k] = 0.0; }

        double pbase = pow(r, (double)(2 * t));
        #pragma unroll
        for (int sub = 0; sub < 2; ++sub) {
            double pb = sub ? pbase * r : pbase;
            #pragma unroll
            for (int i = 0; i < 6; ++i) {
                double pi = gam[i] * pb;
                double ps[4], ssum = 0.0;
                #pragma unroll
                for (int k = 0; k < 4; ++k) {
                    double d0 = pi - C[k];
                    ps[k] = exp(-H[k] * d0 * d0);
                    ssum += ps[k];
                }
                double sc = pi / ssum;
                #pragma unroll
                for (int k = 0; k < 4; ++k) {
                    double sk = ps[k] * sc;
                    qu[sub][k] += vu[i] * sk;
                    qd[sub][k] += vd[i] * sk;
                }
            }
        }
        #pragma unroll
        for (int k = 0; k < 4; ++k) {
            double Qu = m00*qu[0][k] + m01*qd[0][k] + qu[1][k];
            double Qd = m10*qu[0][k] + m11*qd[0][k] + qd[1][k];
            ws[8 + t*8 + k]     = (float)Qu;
            ws[8 + t*8 + 4 + k] = (float)Qd;
        }
    }
    if (t == 49) {
        double gvu = 0.0, gvd = 0.0;
        #pragma unroll
        for (int i = 0; i < 6; ++i) { gvu += vu[i]; gvd += vd[i]; }
        gvu *= 25.0; gvd *= 25.0;
        ws[0] = (float)(m00*m00 + m01*m10);
        ws[1] = (float)(m00*m01 + m01*m11);
        ws[2] = (float)(m10*m00 + m11*m10);
        ws[3] = (float)(m10*m01 + m11*m11);
        ws[4] = (float)((m00 + 1.0)*gvu + m01*gvd);
        ws[5] = (float)(m10*gvu + (m11 + 1.0)*gvd);
        ws[6] = 0.0f; ws[7] = 0.0f;
    }
}

__global__ __launch_bounds__(256) void ndp_main(
    const float* __restrict__ init,   // (B, 32)
    const float* __restrict__ rbfw,   // (B, 64)
    const float* __restrict__ goals,  // (B, 16)
    const float* __restrict__ cst,    // ws
    float* __restrict__ out) {        // (B, 50, 16)
    int tid = blockIdx.x * blockDim.x + threadIdx.x;  // 0..524287
    int b = tid >> 4;
    int a = tid & 15;

    float u  = init[b * 32 + a];
    float ud = init[b * 32 + 16 + a];
    float g  = goals[b * 16 + a];
    float gmu = g - u;

    float4 w = *reinterpret_cast<const float4*>(&rbfw[b * 64 + a * 4]);
    float W0 = gmu * w.x, W1 = gmu * w.y, W2 = gmu * w.z, W3 = gmu * w.w;

    float m00 = cst[0], m01 = cst[1], m10 = cst[2], m11 = cst[3];
    float gcu = g * cst[4], gcd = g * cst[5];

    float* op = out + (size_t)b * 800 + a;
    *op = u;  // t = 0
    const float* q = cst + 8;

    #pragma unroll 7
    for (int m = 0; m < 49; ++m) {
        float4 qu = *reinterpret_cast<const float4*>(q + m * 8);
        float4 qd = *reinterpret_cast<const float4*>(q + m * 8 + 4);
        float fu = gcu + W0*qu.x + W1*qu.y + W2*qu.z + W3*qu.w;
        float fd = gcd + W0*qd.x + W1*qd.y + W2*qd.z + W3*qd.w;
        float un  = m00*u + m01*ud + fu;
        float udn = m10*u + m11*ud + fd;
        u = un; ud = udn;
        op[(m + 1) * 16] = u;
    }
}

extern "C" void kernel_launch(void* const* d_in, const int* in_sizes, int n_in,
                              void* d_out, int out_size, void* d_ws, size_t ws_size,
                              hipStream_t stream) {
    const float* init  = (const float*)d_in[0];
    const float* rbfw  = (const float*)d_in[1];
    const float* goals = (const float*)d_in[2];
    float* out = (float*)d_out;
    float* ws  = (float*)d_ws;

    ndp_setup<<<1, 64, 0, stream>>>(ws);

    const int total = 32768 * 16;            // one thread per (batch, dim)
    ndp_main<<<total / 256, 256, 0, stream>>>(init, rbfw, goals, ws, out);
}